// Round 1
// baseline (336.956 us; speedup 1.0000x reference)
//
#include <hip/hip_runtime.h>
#include <hip/hip_bf16.h>
#include <math.h>

#define H_ 1024
#define NH_ 16
#define HD_ 64
#define B_ 2
#define SQ_ 2048
#define SK_ 2048

using bf16x8 = __attribute__((ext_vector_type(8))) short;
using f32x4  = __attribute__((ext_vector_type(4))) float;

static __device__ __forceinline__ unsigned short f2bf(float f) {
  union { float f; unsigned u; } v; v.f = f;
  unsigned r = v.u + 0x7fffu + ((v.u >> 16) & 1u);
  return (unsigned short)(r >> 16);
}

// ---------------- f32 -> bf16 convert (8 elems/thread) ----------------
__global__ __launch_bounds__(256) void conv_bf16(
    const float* __restrict__ src, unsigned short* __restrict__ dst,
    int rows, int cols, int ld_src, int ld_dst) {
  long total = (long)rows * cols / 8;
  for (long i = blockIdx.x * (long)blockDim.x + threadIdx.x; i < total;
       i += (long)gridDim.x * blockDim.x) {
    long e = i * 8;
    int r = (int)(e / cols);
    int c = (int)(e % cols);
    const float* s = src + (long)r * ld_src + c;
    unsigned short tmp[8];
#pragma unroll
    for (int j = 0; j < 8; ++j) tmp[j] = f2bf(s[j]);
    *(uint4*)(dst + (long)r * ld_dst + c) = *(uint4*)tmp;
  }
}

// ---------------- bf16 GEMM: Out = A(MxK) @ W(KxN) + bias ----------------
// 128x128 tile, 4 waves, BK=32, mfma 16x16x32.
template <bool OUT_BF16, bool GELU>
__global__ __launch_bounds__(256) void gemm_bf16(
    const unsigned short* __restrict__ A, int lda,
    const unsigned short* __restrict__ Bw, int ldb,
    const float* __restrict__ bias,
    void* __restrict__ Out, int ldo, int M, int N, int K) {
  __shared__ __align__(16) unsigned short Al[128][40];
  __shared__ __align__(16) unsigned short Bt[128][40];
  const int tid = threadIdx.x;
  const int l = tid & 63, w = tid >> 6;
  const int wr = w >> 1, wc = w & 1;
  const int lq = l & 15, lh = l >> 4;
  const int m0 = blockIdx.y * 128, n0 = blockIdx.x * 128;

  f32x4 acc[4][4];
#pragma unroll
  for (int a = 0; a < 4; ++a)
#pragma unroll
    for (int b = 0; b < 4; ++b) acc[a][b] = (f32x4){0.f, 0.f, 0.f, 0.f};

  for (int k0 = 0; k0 < K; k0 += 32) {
    {  // stage A tile (128x32) row-major
      int r = tid >> 1, c = (tid & 1) * 16;
      const unsigned short* g = A + (long)(m0 + r) * lda + k0 + c;
      *(uint4*)&Al[r][c] = *(const uint4*)g;
      *(uint4*)&Al[r][c + 8] = *(const uint4*)(g + 8);
    }
    {  // stage B tile transposed: Bt[n][k]
      int kr = tid >> 3, c0 = (tid & 7) * 16;
      const unsigned short* g = Bw + (long)(k0 + kr) * ldb + n0 + c0;
      uint4 v0 = *(const uint4*)g;
      uint4 v1 = *(const uint4*)(g + 8);
      const unsigned short* p0 = (const unsigned short*)&v0;
      const unsigned short* p1 = (const unsigned short*)&v1;
#pragma unroll
      for (int j = 0; j < 8; ++j) Bt[c0 + j][kr] = p0[j];
#pragma unroll
      for (int j = 0; j < 8; ++j) Bt[c0 + 8 + j][kr] = p1[j];
    }
    __syncthreads();
    bf16x8 af[4], bfr[4];
#pragma unroll
    for (int a = 0; a < 4; ++a)
      af[a] = *(const bf16x8*)&Al[wr * 64 + a * 16 + lq][lh * 8];
#pragma unroll
    for (int b = 0; b < 4; ++b)
      bfr[b] = *(const bf16x8*)&Bt[wc * 64 + b * 16 + lq][lh * 8];
#pragma unroll
    for (int a = 0; a < 4; ++a)
#pragma unroll
      for (int b = 0; b < 4; ++b)
        acc[a][b] = __builtin_amdgcn_mfma_f32_16x16x32_bf16(af[a], bfr[b], acc[a][b], 0, 0, 0);
    __syncthreads();
  }

#pragma unroll
  for (int a = 0; a < 4; ++a) {
#pragma unroll
    for (int b = 0; b < 4; ++b) {
      int col = n0 + wc * 64 + b * 16 + lq;
      float bv = bias[col];
#pragma unroll
      for (int r = 0; r < 4; ++r) {
        int row = m0 + wr * 64 + a * 16 + lh * 4 + r;
        float v = acc[a][b][r] + bv;
        if (GELU) {
          float t = tanhf(0.7978845608028654f * (v + 0.044715f * v * v * v));
          v = 0.5f * v * (1.f + t);
        }
        if (OUT_BF16)
          ((unsigned short*)Out)[(long)row * ldo + col] = f2bf(v);
        else
          ((float*)Out)[(long)row * ldo + col] = v;
      }
    }
  }
}

// ---------------- flash attention (swapped-operand, multiplicative mask) ----------------
// grid: (SQ/64, NH, B), block 256 (4 waves, 16 q-rows each). KV tiles of 64.
__global__ __launch_bounds__(256) void flash_attn(
    const unsigned short* __restrict__ Qb,   // (B*SQ, H)
    const unsigned short* __restrict__ KVb,  // (B*SK, 2H): K cols [0,H), V cols [H,2H)
    const int* __restrict__ mask,            // (B, SK)
    unsigned short* __restrict__ Ob) {       // (B*SQ, H)
  __shared__ __align__(16) unsigned short Kl[64][72];
  __shared__ __align__(16) unsigned short Vt[64][72];  // Vt[d][k]
  __shared__ __align__(16) unsigned short Pl[4][16][72];
  __shared__ float Ml[64];
  const int tid = threadIdx.x;
  const int l = tid & 63, w = tid >> 6;
  const int qb = blockIdx.x, h = blockIdx.y, b = blockIdx.z;
  const int lq = l & 15, lh = l >> 4;

  bf16x8 qf[2];
  {
    long qrow = (long)b * SQ_ + qb * 64 + w * 16 + lq;
    const unsigned short* qp = Qb + qrow * H_ + h * HD_;
    qf[0] = *(const bf16x8*)(qp + lh * 8);
    qf[1] = *(const bf16x8*)(qp + 32 + lh * 8);
  }
  float m_run = -INFINITY, l_run = 0.f;
  f32x4 accO[4];
#pragma unroll
  for (int ms = 0; ms < 4; ++ms) accO[ms] = (f32x4){0.f, 0.f, 0.f, 0.f};

  for (int kt = 0; kt < SK_ / 64; ++kt) {
    {  // stage K tile + transposed V tile
      int r = tid >> 2, c = (tid & 3) * 16;
      long krow = (long)b * SK_ + kt * 64 + r;
      const unsigned short* kp = KVb + krow * (2 * H_) + h * HD_ + c;
      *(uint4*)&Kl[r][c] = *(const uint4*)kp;
      *(uint4*)&Kl[r][c + 8] = *(const uint4*)(kp + 8);
      const unsigned short* vp = KVb + krow * (2 * H_) + H_ + h * HD_ + c;
      uint4 v0 = *(const uint4*)vp;
      uint4 v1 = *(const uint4*)(vp + 8);
      const unsigned short* p0 = (const unsigned short*)&v0;
      const unsigned short* p1 = (const unsigned short*)&v1;
#pragma unroll
      for (int j = 0; j < 8; ++j) Vt[c + j][r] = p0[j];
#pragma unroll
      for (int j = 0; j < 8; ++j) Vt[c + 8 + j][r] = p1[j];
      if (tid < 64) Ml[tid] = (float)mask[(long)b * SK_ + kt * 64 + tid];
    }
    __syncthreads();

    // S^T(64k x 16q) = K_tile @ Q^T
    f32x4 s[4];
#pragma unroll
    for (int ms = 0; ms < 4; ++ms) {
      f32x4 z = (f32x4){0.f, 0.f, 0.f, 0.f};
      bf16x8 a0 = *(const bf16x8*)&Kl[ms * 16 + lq][lh * 8];
      bf16x8 a1 = *(const bf16x8*)&Kl[ms * 16 + lq][32 + lh * 8];
      z = __builtin_amdgcn_mfma_f32_16x16x32_bf16(a0, qf[0], z, 0, 0, 0);
      z = __builtin_amdgcn_mfma_f32_16x16x32_bf16(a1, qf[1], z, 0, 0, 0);
      s[ms] = z;
    }
    // multiplicative mask + online softmax (lane-local per q)
    float tmax = -INFINITY;
#pragma unroll
    for (int ms = 0; ms < 4; ++ms)
#pragma unroll
      for (int r = 0; r < 4; ++r) {
        float sv = s[ms][r] * Ml[ms * 16 + lh * 4 + r];
        s[ms][r] = sv;
        tmax = fmaxf(tmax, sv);
      }
    tmax = fmaxf(tmax, __shfl_xor(tmax, 16));
    tmax = fmaxf(tmax, __shfl_xor(tmax, 32));
    float m_new = fmaxf(m_run, tmax);
    float sc = __expf(m_run - m_new);
    m_run = m_new;
    float lsum = 0.f;
    unsigned long long pk[4];
#pragma unroll
    for (int ms = 0; ms < 4; ++ms) {
      unsigned short pu[4];
#pragma unroll
      for (int r = 0; r < 4; ++r) {
        float p = __expf(s[ms][r] - m_new);
        lsum += p;
        pu[r] = f2bf(p);
      }
      pk[ms] = *(unsigned long long*)pu;
    }
    lsum += __shfl_xor(lsum, 16);
    lsum += __shfl_xor(lsum, 32);
    l_run = l_run * sc + lsum;
#pragma unroll
    for (int ms = 0; ms < 4; ++ms) {
#pragma unroll
      for (int r = 0; r < 4; ++r) accO[ms][r] *= sc;
      *(unsigned long long*)&Pl[w][lq][ms * 16 + lh * 4] = pk[ms];
    }
    // O^T(64d x 16q) += V^T @ P^T
#pragma unroll
    for (int ms = 0; ms < 4; ++ms) {
      bf16x8 a0 = *(const bf16x8*)&Vt[ms * 16 + lq][lh * 8];
      bf16x8 a1 = *(const bf16x8*)&Vt[ms * 16 + lq][32 + lh * 8];
      bf16x8 b0 = *(const bf16x8*)&Pl[w][lq][lh * 8];
      bf16x8 b1 = *(const bf16x8*)&Pl[w][lq][32 + lh * 8];
      accO[ms] = __builtin_amdgcn_mfma_f32_16x16x32_bf16(a0, b0, accO[ms], 0, 0, 0);
      accO[ms] = __builtin_amdgcn_mfma_f32_16x16x32_bf16(a1, b1, accO[ms], 0, 0, 0);
    }
    __syncthreads();
  }

  float rs = 1.f / l_run;
  long orow = (long)b * SQ_ + qb * 64 + w * 16 + lq;
#pragma unroll
  for (int ms = 0; ms < 4; ++ms) {
    unsigned short ou[4];
#pragma unroll
    for (int r = 0; r < 4; ++r) ou[r] = f2bf(accO[ms][r] * rs);
    *(unsigned long long*)(Ob + orow * H_ + h * HD_ + ms * 16 + lh * 4) =
        *(unsigned long long*)ou;
  }
}

extern "C" void kernel_launch(void* const* d_in, const int* in_sizes, int n_in,
                              void* d_out, int out_size, void* d_ws, size_t ws_size,
                              hipStream_t stream) {
  (void)in_sizes; (void)n_in; (void)out_size; (void)ws_size;
  const float* attender = (const float*)d_in[0];
  const float* attendee = (const float*)d_in[1];
  const int*   mask     = (const int*)d_in[2];
  const float* c_attn_b = (const float*)d_in[4];
  const float* c_attn_w = (const float*)d_in[3];
  const float* c_proj_w = (const float*)d_in[5];
  const float* c_proj_b = (const float*)d_in[6];
  const float* mlp_w    = (const float*)d_in[7];
  const float* mlp_b    = (const float*)d_in[8];
  float* out = (float*)d_out;

  char* ws = (char*)d_ws;
  size_t off = 0;
  auto alloc = [&](size_t bytes) {
    void* p = ws + off;
    off += (bytes + 255) & ~(size_t)255;
    return p;
  };
  unsigned short* cat   = (unsigned short*)alloc((size_t)4096 * 2048 * 2); // [attender_bf | proj_bf]
  unsigned short* aet   = (unsigned short*)alloc((size_t)4096 * 1024 * 2);
  unsigned short* w_at  = (unsigned short*)alloc((size_t)1024 * 3072 * 2);
  unsigned short* w_pr  = (unsigned short*)alloc((size_t)1024 * 1024 * 2);
  unsigned short* w_ml  = (unsigned short*)alloc((size_t)2048 * 1024 * 2);
  unsigned short* Qb    = (unsigned short*)alloc((size_t)4096 * 1024 * 2);
  unsigned short* KVb   = (unsigned short*)alloc((size_t)4096 * 2048 * 2);
  unsigned short* attnb = (unsigned short*)alloc((size_t)4096 * 1024 * 2);

  conv_bf16<<<2048, 256, 0, stream>>>(attender, cat, 4096, 1024, 1024, 2048);
  conv_bf16<<<2048, 256, 0, stream>>>(attendee, aet, 4096, 1024, 1024, 1024);
  conv_bf16<<<1536, 256, 0, stream>>>(c_attn_w, w_at, 1024, 3072, 3072, 3072);
  conv_bf16<<<512,  256, 0, stream>>>(c_proj_w, w_pr, 1024, 1024, 1024, 1024);
  conv_bf16<<<1024, 256, 0, stream>>>(mlp_w,    w_ml, 2048, 1024, 1024, 1024);

  // Q = attender @ W[:, :H] + b[:H]
  gemm_bf16<true, false><<<dim3(8, 32), 256, 0, stream>>>(
      cat, 2048, w_at, 3072, c_attn_b, Qb, 1024, 4096, 1024, 1024);
  // KV = attendee @ W[:, H:3H] + b[H:3H]
  gemm_bf16<true, false><<<dim3(16, 32), 256, 0, stream>>>(
      aet, 1024, w_at + 1024, 3072, c_attn_b + 1024, KVb, 2048, 4096, 2048, 1024);
  // attention
  flash_attn<<<dim3(32, 16, 2), 256, 0, stream>>>(Qb, KVb, mask, attnb);
  // proj -> cat[:, H:2H]
  gemm_bf16<true, false><<<dim3(8, 32), 256, 0, stream>>>(
      attnb, 1024, w_pr, 1024, c_proj_b, cat + 1024, 2048, 4096, 1024, 1024);
  // out = gelu(cat @ mlp_w + mlp_b), f32
  gemm_bf16<false, true><<<dim3(8, 32), 256, 0, stream>>>(
      cat, 2048, w_ml, 1024, mlp_b, out, 1024, 4096, 1024, 2048);
}

// Round 2
// 243.187 us; speedup vs baseline: 1.3856x; 1.3856x over previous
//
#include <hip/hip_runtime.h>
#include <hip/hip_bf16.h>
#include <math.h>

#define H_ 1024
#define NH_ 16
#define HD_ 64
#define B_ 2
#define SQ_ 2048
#define SK_ 2048

using bf16x8 = __attribute__((ext_vector_type(8))) short;
using f32x4  = __attribute__((ext_vector_type(4))) float;

static __device__ __forceinline__ unsigned short f2bf(float f) {
  union { float f; unsigned u; } v; v.f = f;
  unsigned r = v.u + 0x7fffu + ((v.u >> 16) & 1u);
  return (unsigned short)(r >> 16);
}

static __device__ __forceinline__ void gl2lds16(const void* g, void* l) {
  __builtin_amdgcn_global_load_lds(
      (const __attribute__((address_space(1))) unsigned int*)g,
      (__attribute__((address_space(3))) unsigned int*)l, 16, 0, 0);
}

// ---------------- f32 -> bf16 convert (8 elems/thread) ----------------
__global__ __launch_bounds__(256) void conv_bf16(
    const float* __restrict__ src, unsigned short* __restrict__ dst,
    int rows, int cols, int ld_src, int ld_dst) {
  long total = (long)rows * cols / 8;
  for (long i = blockIdx.x * (long)blockDim.x + threadIdx.x; i < total;
       i += (long)gridDim.x * blockDim.x) {
    long e = i * 8;
    int r = (int)(e / cols);
    int c = (int)(e % cols);
    const float* s = src + (long)r * ld_src + c;
    unsigned short tmp[8];
#pragma unroll
    for (int j = 0; j < 8; ++j) tmp[j] = f2bf(s[j]);
    *(uint4*)(dst + (long)r * ld_dst + c) = *(uint4*)tmp;
  }
}

// ---------------- f32 (R,C) -> bf16 transposed (C,R) ----------------
__global__ __launch_bounds__(256) void convT(
    const float* __restrict__ in, unsigned short* __restrict__ out, int R, int C) {
  __shared__ __align__(16) unsigned short Ls[64][68];
  int nct = C >> 6;
  int tr = blockIdx.x / nct, tc = blockIdx.x % nct;
  int r0 = tr * 64, c0 = tc * 64;
  int rr = threadIdx.x >> 4;
  int cc = (threadIdx.x & 15) * 4;
#pragma unroll
  for (int i = 0; i < 4; ++i) {
    int r = rr + 16 * i;
    float4 v = *(const float4*)&in[(long)(r0 + r) * C + c0 + cc];
    unsigned short t[4] = {f2bf(v.x), f2bf(v.y), f2bf(v.z), f2bf(v.w)};
    *(unsigned long long*)&Ls[r][cc] = *(unsigned long long*)t;
  }
  __syncthreads();
  int oc = threadIdx.x >> 2;
  int orr = (threadIdx.x & 3) * 16;
  unsigned short t[16];
#pragma unroll
  for (int j = 0; j < 16; ++j) t[j] = Ls[orr + j][oc];
  *(uint4*)&out[(long)(c0 + oc) * R + r0 + orr] = *(uint4*)&t[0];
  *(uint4*)&out[(long)(c0 + oc) * R + r0 + orr + 8] = *(uint4*)&t[8];
}

// ---------------- bf16 GEMM, B^T input (m97 structure) ----------------
// Out = A(MxK) @ W(KxN) + bias, where Bw = W^T (N rows, K cols).
// MODE 0: bf16 out0.  MODE 1: f32 out0 + GELU.  MODE 2: split KV:
//   col < H -> bf16 normal to out0 (K buffer); col >= H -> V transposed to
//   out1 laid out (B, NH, HD, SK), packed 4-k stores.
template <int MODE>
__global__ __launch_bounds__(256) void gemm_bt(
    const unsigned short* __restrict__ A, int lda,
    const unsigned short* __restrict__ Bw, int ldb,
    const float* __restrict__ bias,
    void* __restrict__ out0, void* __restrict__ out1, int ldo,
    int M, int N, int K) {
  __shared__ __align__(16) unsigned short Al[128 * 32];
  __shared__ __align__(16) unsigned short Bl[128 * 32];
  const int tid = threadIdx.x;
  const int l = tid & 63, w = tid >> 6;
  const int wr = w >> 1, wc = w & 1;
  const int lq = l & 15, lh = l >> 4;
  const int m0 = blockIdx.y * 128, n0 = blockIdx.x * 128;

  const int cb = w * 2048;  // byte base of this wave's chunk pair
  const int o0 = cb + l * 16, o1 = o0 + 1024;
  const int r0s = o0 >> 6, c0s = (o0 & 63) >> 1;
  const int r1s = o1 >> 6, c1s = (o1 & 63) >> 1;
  const unsigned short* gA0 = A + (long)(m0 + r0s) * lda + c0s;
  const unsigned short* gA1 = A + (long)(m0 + r1s) * lda + c1s;
  const unsigned short* gB0 = Bw + (long)(n0 + r0s) * ldb + c0s;
  const unsigned short* gB1 = Bw + (long)(n0 + r1s) * ldb + c1s;
  unsigned short* lA0 = (unsigned short*)((char*)Al + cb);
  unsigned short* lA1 = (unsigned short*)((char*)Al + cb + 1024);
  unsigned short* lB0 = (unsigned short*)((char*)Bl + cb);
  unsigned short* lB1 = (unsigned short*)((char*)Bl + cb + 1024);

  f32x4 acc[4][4];
#pragma unroll
  for (int a = 0; a < 4; ++a)
#pragma unroll
    for (int b = 0; b < 4; ++b) acc[a][b] = (f32x4){0.f, 0.f, 0.f, 0.f};

  for (int k0 = 0; k0 < K; k0 += 32) {
    gl2lds16(gA0 + k0, lA0);
    gl2lds16(gA1 + k0, lA1);
    gl2lds16(gB0 + k0, lB0);
    gl2lds16(gB1 + k0, lB1);
    __syncthreads();
    bf16x8 af[4], bfr[4];
#pragma unroll
    for (int a = 0; a < 4; ++a)
      af[a] = *(const bf16x8*)&Al[(wr * 64 + a * 16 + lq) * 32 + lh * 8];
#pragma unroll
    for (int b = 0; b < 4; ++b)
      bfr[b] = *(const bf16x8*)&Bl[(wc * 64 + b * 16 + lq) * 32 + lh * 8];
#pragma unroll
    for (int a = 0; a < 4; ++a)
#pragma unroll
      for (int b = 0; b < 4; ++b)
        acc[a][b] = __builtin_amdgcn_mfma_f32_16x16x32_bf16(af[a], bfr[b], acc[a][b], 0, 0, 0);
    __syncthreads();
  }

#pragma unroll
  for (int a = 0; a < 4; ++a) {
#pragma unroll
    for (int bb = 0; bb < 4; ++bb) {
      int col = n0 + wc * 64 + bb * 16 + lq;
      float bv = bias[col];
      int row0 = m0 + wr * 64 + a * 16 + lh * 4;
      if (MODE == 0) {
        unsigned short* O = (unsigned short*)out0;
#pragma unroll
        for (int r = 0; r < 4; ++r)
          O[(long)(row0 + r) * ldo + col] = f2bf(acc[a][bb][r] + bv);
      } else if (MODE == 1) {
        float* O = (float*)out0;
#pragma unroll
        for (int r = 0; r < 4; ++r) {
          float v = acc[a][bb][r] + bv;
          float y = 0.7978845608028654f * (v + 0.044715f * v * v * v);
          O[(long)(row0 + r) * ldo + col] =
              v * __builtin_amdgcn_rcpf(1.f + __expf(-2.f * y));
        }
      } else {
        if (col < H_) {
          unsigned short* O = (unsigned short*)out0;
#pragma unroll
          for (int r = 0; r < 4; ++r)
            O[(long)(row0 + r) * ldo + col] = f2bf(acc[a][bb][r] + bv);
        } else {
          int vcol = col - H_, hh = vcol >> 6, dd = vcol & 63;
          int bi = row0 >> 11, k = row0 & 2047;
          unsigned short t[4];
#pragma unroll
          for (int r = 0; r < 4; ++r) t[r] = f2bf(acc[a][bb][r] + bv);
          *(unsigned long long*)((unsigned short*)out1 +
                                 (((long)(bi * NH_ + hh) * HD_ + dd) << 11) + k) =
              *(unsigned long long*)t;
        }
      }
    }
  }
}

// ---------------- flash attention (swapped-operand, multiplicative mask) ----------------
// grid: (SQ/64, NH, B), block 256 (4 waves x 16 q-rows). KV tiles of 64.
// K from (B*SK, H) buffer; V pre-transposed (B, NH, HD, SK).
__global__ __launch_bounds__(256) void flash_attn(
    const unsigned short* __restrict__ Qb,
    const unsigned short* __restrict__ Kb,
    const unsigned short* __restrict__ Vtg,
    const int* __restrict__ mask,
    unsigned short* __restrict__ Ob) {
  __shared__ __align__(16) unsigned short Kl[64][72];
  __shared__ __align__(16) unsigned short Vt[64][72];  // Vt[d][k]
  __shared__ __align__(16) unsigned short Pl[4][16][72];
  __shared__ float Ml[64];
  const int tid = threadIdx.x;
  const int l = tid & 63, w = tid >> 6;
  const int qb = blockIdx.x, h = blockIdx.y, b = blockIdx.z;
  const int lq = l & 15, lh = l >> 4;

  bf16x8 qf[2];
  {
    long qrow = (long)b * SQ_ + qb * 64 + w * 16 + lq;
    const unsigned short* qp = Qb + qrow * H_ + h * HD_;
    qf[0] = *(const bf16x8*)(qp + lh * 8);
    qf[1] = *(const bf16x8*)(qp + 32 + lh * 8);
  }

  const int sr = tid >> 2, sc = (tid & 3) * 16;
  const unsigned short* Kg = Kb + ((long)b * SK_ + sr) * H_ + h * HD_ + sc;
  const unsigned short* Vg = Vtg + ((long)(b * NH_ + h) * HD_ + sr) * SK_ + sc;

  // prologue: tile 0 into regs, then LDS
  uint4 kr0 = *(const uint4*)Kg, kr1 = *(const uint4*)(Kg + 8);
  uint4 vr0 = *(const uint4*)Vg, vr1 = *(const uint4*)(Vg + 8);
  int mreg = (tid < 64) ? mask[(long)b * SK_ + tid] : 0;
  *(uint4*)&Kl[sr][sc] = kr0;
  *(uint4*)&Kl[sr][sc + 8] = kr1;
  *(uint4*)&Vt[sr][sc] = vr0;
  *(uint4*)&Vt[sr][sc + 8] = vr1;
  if (tid < 64) Ml[tid] = (float)mreg;

  float m_run = -INFINITY, l_run = 0.f;
  f32x4 accO[4];
#pragma unroll
  for (int ms = 0; ms < 4; ++ms) accO[ms] = (f32x4){0.f, 0.f, 0.f, 0.f};

  const int NT = SK_ / 64;
  for (int kt = 0; kt < NT; ++kt) {
    __syncthreads();  // staged tile visible
    if (kt + 1 < NT) {  // prefetch next tile (overlaps compute)
      kr0 = *(const uint4*)(Kg + (long)(kt + 1) * 64 * H_);
      kr1 = *(const uint4*)(Kg + (long)(kt + 1) * 64 * H_ + 8);
      vr0 = *(const uint4*)(Vg + (kt + 1) * 64);
      vr1 = *(const uint4*)(Vg + (kt + 1) * 64 + 8);
      mreg = (tid < 64) ? mask[(long)b * SK_ + (kt + 1) * 64 + tid] : 0;
    }

    // S^T(64k x 16q) = K_tile @ Q^T
    f32x4 s[4];
#pragma unroll
    for (int ms = 0; ms < 4; ++ms) {
      f32x4 z = (f32x4){0.f, 0.f, 0.f, 0.f};
      bf16x8 a0 = *(const bf16x8*)&Kl[ms * 16 + lq][lh * 8];
      bf16x8 a1 = *(const bf16x8*)&Kl[ms * 16 + lq][32 + lh * 8];
      z = __builtin_amdgcn_mfma_f32_16x16x32_bf16(a0, qf[0], z, 0, 0, 0);
      z = __builtin_amdgcn_mfma_f32_16x16x32_bf16(a1, qf[1], z, 0, 0, 0);
      s[ms] = z;
    }
    // multiplicative mask + online softmax (lane-local per q)
    float tmax = -INFINITY;
#pragma unroll
    for (int ms = 0; ms < 4; ++ms) {
      f32x4 mv = *(const f32x4*)&Ml[ms * 16 + lh * 4];
#pragma unroll
      for (int r = 0; r < 4; ++r) {
        float sv = s[ms][r] * mv[r];
        s[ms][r] = sv;
        tmax = fmaxf(tmax, sv);
      }
    }
    tmax = fmaxf(tmax, __shfl_xor(tmax, 16));
    tmax = fmaxf(tmax, __shfl_xor(tmax, 32));
    float m_new = fmaxf(m_run, tmax);
    float sc_ = __expf(m_run - m_new);
    m_run = m_new;
    float lsum = 0.f;
    unsigned long long pk[4];
#pragma unroll
    for (int ms = 0; ms < 4; ++ms) {
      unsigned short pu[4];
#pragma unroll
      for (int r = 0; r < 4; ++r) {
        float p = __expf(s[ms][r] - m_new);
        lsum += p;
        pu[r] = f2bf(p);
      }
      pk[ms] = *(unsigned long long*)pu;
    }
    lsum += __shfl_xor(lsum, 16);
    lsum += __shfl_xor(lsum, 32);
    l_run = l_run * sc_ + lsum;
#pragma unroll
    for (int ms = 0; ms < 4; ++ms) {
#pragma unroll
      for (int r = 0; r < 4; ++r) accO[ms][r] *= sc_;
      *(unsigned long long*)&Pl[w][lq][ms * 16 + lh * 4] = pk[ms];
    }
    // O^T(64d x 16q) += V^T @ P^T  (P fragments hoisted)
    bf16x8 pb0 = *(const bf16x8*)&Pl[w][lq][lh * 8];
    bf16x8 pb1 = *(const bf16x8*)&Pl[w][lq][32 + lh * 8];
#pragma unroll
    for (int ms = 0; ms < 4; ++ms) {
      bf16x8 a0 = *(const bf16x8*)&Vt[ms * 16 + lq][lh * 8];
      bf16x8 a1 = *(const bf16x8*)&Vt[ms * 16 + lq][32 + lh * 8];
      accO[ms] = __builtin_amdgcn_mfma_f32_16x16x32_bf16(a0, pb0, accO[ms], 0, 0, 0);
      accO[ms] = __builtin_amdgcn_mfma_f32_16x16x32_bf16(a1, pb1, accO[ms], 0, 0, 0);
    }
    __syncthreads();  // all reads of this tile done
    if (kt + 1 < NT) {
      *(uint4*)&Kl[sr][sc] = kr0;
      *(uint4*)&Kl[sr][sc + 8] = kr1;
      *(uint4*)&Vt[sr][sc] = vr0;
      *(uint4*)&Vt[sr][sc + 8] = vr1;
      if (tid < 64) Ml[tid] = (float)mreg;
    }
  }

  float rs = 1.f / l_run;
  long orow = (long)b * SQ_ + qb * 64 + w * 16 + lq;
#pragma unroll
  for (int ms = 0; ms < 4; ++ms) {
    unsigned short ou[4];
#pragma unroll
    for (int r = 0; r < 4; ++r) ou[r] = f2bf(accO[ms][r] * rs);
    *(unsigned long long*)(Ob + orow * H_ + h * HD_ + ms * 16 + lh * 4) =
        *(unsigned long long*)ou;
  }
}

extern "C" void kernel_launch(void* const* d_in, const int* in_sizes, int n_in,
                              void* d_out, int out_size, void* d_ws, size_t ws_size,
                              hipStream_t stream) {
  (void)in_sizes; (void)n_in; (void)out_size; (void)ws_size;
  const float* attender = (const float*)d_in[0];
  const float* attendee = (const float*)d_in[1];
  const int*   mask     = (const int*)d_in[2];
  const float* c_attn_w = (const float*)d_in[3];
  const float* c_attn_b = (const float*)d_in[4];
  const float* c_proj_w = (const float*)d_in[5];
  const float* c_proj_b = (const float*)d_in[6];
  const float* mlp_w    = (const float*)d_in[7];
  const float* mlp_b    = (const float*)d_in[8];
  float* out = (float*)d_out;

  char* ws = (char*)d_ws;
  size_t off = 0;
  auto alloc = [&](size_t bytes) {
    void* p = ws + off;
    off += (bytes + 255) & ~(size_t)255;
    return p;
  };
  unsigned short* cat   = (unsigned short*)alloc((size_t)4096 * 2048 * 2); // [attender_bf | proj_bf]
  unsigned short* aet   = (unsigned short*)alloc((size_t)4096 * 1024 * 2);
  unsigned short* w_atT = (unsigned short*)alloc((size_t)3072 * 1024 * 2); // (3H, H)
  unsigned short* w_prT = (unsigned short*)alloc((size_t)1024 * 1024 * 2);
  unsigned short* w_mlT = (unsigned short*)alloc((size_t)1024 * 2048 * 2); // (H, 2H)
  unsigned short* Qb    = (unsigned short*)alloc((size_t)4096 * 1024 * 2);
  unsigned short* Kbuf  = (unsigned short*)alloc((size_t)4096 * 1024 * 2);
  unsigned short* Vtg   = (unsigned short*)alloc((size_t)B_ * NH_ * HD_ * SK_ * 2);
  unsigned short* attnb = (unsigned short*)alloc((size_t)4096 * 1024 * 2);

  conv_bf16<<<2048, 256, 0, stream>>>(attender, cat, 4096, 1024, 1024, 2048);
  conv_bf16<<<2048, 256, 0, stream>>>(attendee, aet, 4096, 1024, 1024, 1024);
  convT<<<768, 256, 0, stream>>>(c_attn_w, w_atT, 1024, 3072);
  convT<<<256, 256, 0, stream>>>(c_proj_w, w_prT, 1024, 1024);
  convT<<<512, 256, 0, stream>>>(mlp_w, w_mlT, 2048, 1024);

  // Q = attender @ W[:, :H] + b[:H]
  gemm_bt<0><<<dim3(8, 32), 256, 0, stream>>>(
      cat, 2048, w_atT, 1024, c_attn_b, Qb, nullptr, 1024, 4096, 1024, 1024);
  // K,V = attendee @ W[:, H:3H] + b[H:3H]; K normal, V transposed
  gemm_bt<2><<<dim3(16, 32), 256, 0, stream>>>(
      aet, 1024, w_atT + (size_t)1024 * 1024, 1024, c_attn_b + 1024,
      Kbuf, Vtg, 1024, 4096, 2048, 1024);
  // attention
  flash_attn<<<dim3(32, 16, 2), 256, 0, stream>>>(Qb, Kbuf, Vtg, mask, attnb);
  // proj -> cat[:, H:2H]
  gemm_bt<0><<<dim3(8, 32), 256, 0, stream>>>(
      attnb, 1024, w_prT, 1024, c_proj_b, cat + 1024, nullptr, 2048, 4096, 1024, 1024);
  // out = gelu(cat @ mlp_w + mlp_b), f32
  gemm_bt<1><<<dim3(8, 32), 256, 0, stream>>>(
      cat, 2048, w_mlT, 2048, mlp_b, out, nullptr, 1024, 4096, 1024, 2048);
}

// Round 3
// 237.459 us; speedup vs baseline: 1.4190x; 1.0241x over previous
//
#include <hip/hip_runtime.h>
#include <hip/hip_bf16.h>
#include <math.h>

#define H_ 1024
#define NH_ 16
#define HD_ 64
#define B_ 2
#define SQ_ 2048
#define SK_ 2048

using bf16x8 = __attribute__((ext_vector_type(8))) short;
using f32x4  = __attribute__((ext_vector_type(4))) float;

static __device__ __forceinline__ unsigned short f2bf(float f) {
  union { float f; unsigned u; } v; v.f = f;
  unsigned r = v.u + 0x7fffu + ((v.u >> 16) & 1u);
  return (unsigned short)(r >> 16);
}

static __device__ __forceinline__ void gl2lds16(const void* g, void* l) {
  __builtin_amdgcn_global_load_lds(
      (const __attribute__((address_space(1))) unsigned int*)g,
      (__attribute__((address_space(3))) unsigned int*)l, 16, 0, 0);
}

// swizzled index (shorts) within a [rows][64-short] tile, 128B rows
static __device__ __forceinline__ int sidx(int row, int cbyte) {
  return row * 64 + (((cbyte) ^ ((row & 7) << 4)) >> 1);
}

// ---------------- f32 -> bf16 convert (8 elems/thread) ----------------
__global__ __launch_bounds__(256) void conv_bf16(
    const float* __restrict__ src, unsigned short* __restrict__ dst,
    int rows, int cols, int ld_src, int ld_dst) {
  long total = (long)rows * cols / 8;
  for (long i = blockIdx.x * (long)blockDim.x + threadIdx.x; i < total;
       i += (long)gridDim.x * blockDim.x) {
    long e = i * 8;
    int r = (int)(e / cols);
    int c = (int)(e % cols);
    const float* s = src + (long)r * ld_src + c;
    unsigned short tmp[8];
#pragma unroll
    for (int j = 0; j < 8; ++j) tmp[j] = f2bf(s[j]);
    *(uint4*)(dst + (long)r * ld_dst + c) = *(uint4*)tmp;
  }
}

// ---------------- f32 (R,C) -> bf16 transposed (C,R) ----------------
__global__ __launch_bounds__(256) void convT(
    const float* __restrict__ in, unsigned short* __restrict__ out, int R, int C) {
  __shared__ __align__(16) unsigned short Ls[64][68];
  int nct = C >> 6;
  int tr = blockIdx.x / nct, tc = blockIdx.x % nct;
  int r0 = tr * 64, c0 = tc * 64;
  int rr = threadIdx.x >> 4;
  int cc = (threadIdx.x & 15) * 4;
#pragma unroll
  for (int i = 0; i < 4; ++i) {
    int r = rr + 16 * i;
    float4 v = *(const float4*)&in[(long)(r0 + r) * C + c0 + cc];
    unsigned short t[4] = {f2bf(v.x), f2bf(v.y), f2bf(v.z), f2bf(v.w)};
    *(unsigned long long*)&Ls[r][cc] = *(unsigned long long*)t;
  }
  __syncthreads();
  int oc = threadIdx.x >> 2;
  int orr = (threadIdx.x & 3) * 16;
  unsigned short t[16];
#pragma unroll
  for (int j = 0; j < 16; ++j) t[j] = Ls[orr + j][oc];
  *(uint4*)&out[(long)(c0 + oc) * R + r0 + orr] = *(uint4*)&t[0];
  *(uint4*)&out[(long)(c0 + oc) * R + r0 + orr + 8] = *(uint4*)&t[8];
}

// ---------------- bf16 GEMM, B^T input, BK=64, double-buffered, swizzled ----
// Out = A(MxK) @ W(KxN) + bias, Bw = W^T (N rows, K cols). BN = NF*32.
// MODE 0: bf16 out0.  MODE 1: f32 out0 + GELU.  MODE 2: split KV (col<H ->
// bf16 K to out0; col>=H -> V transposed to out1 (B,NH,HD,SK)).
template <int NF, int MODE>
__global__ __launch_bounds__(256) void gemm_bt(
    const unsigned short* __restrict__ A, int lda,
    const unsigned short* __restrict__ Bw, int ldb,
    const float* __restrict__ bias,
    void* __restrict__ out0, void* __restrict__ out1, int ldo,
    int M, int N, int K) {
  __shared__ __align__(16) unsigned short Al[2][128 * 64];
  __shared__ __align__(16) unsigned short Bl[2][NF * 32 * 64];
  const int tid = threadIdx.x;
  const int l = tid & 63, w = tid >> 6;
  const int wr = w >> 1, wc = w & 1;
  const int lq = l & 15, lh = l >> 4;
  const int m0 = blockIdx.y * 128, n0 = blockIdx.x * (NF * 32);

  // pre-swizzled global source (rule #21: linear LDS dest + inv-swizzled src)
  const int swcol = (((tid & 7) ^ ((tid >> 3) & 7)) << 3);  // shorts
  const int rbase = w * 8 + ((l & 63) >> 3);                // wait: (tid&63)>>3
  const unsigned short* gA = A + (long)(m0 + rbase) * lda + swcol;
  const unsigned short* gB = Bw + (long)(n0 + rbase) * ldb + swcol;

  f32x4 acc[4][NF];
#pragma unroll
  for (int a = 0; a < 4; ++a)
#pragma unroll
    for (int b = 0; b < NF; ++b) acc[a][b] = (f32x4){0.f, 0.f, 0.f, 0.f};

  auto stage = [&](int k0, int buf) {
#pragma unroll
    for (int i = 0; i < 4; ++i)
      gl2lds16(gA + (long)(i * 32) * lda + k0, &Al[buf][i * 2048 + w * 512]);
#pragma unroll
    for (int i = 0; i < NF; ++i)
      gl2lds16(gB + (long)(i * 32) * ldb + k0, &Bl[buf][i * 2048 + w * 512]);
  };

  const int NT = K >> 6;
  stage(0, 0);
  __syncthreads();
  int cur = 0;
  for (int t = 0; t < NT; ++t) {
    if (t + 1 < NT) stage((t + 1) << 6, cur ^ 1);
    bf16x8 af[4][2], bfr[NF][2];
#pragma unroll
    for (int a = 0; a < 4; ++a) {
      int row = wr * 64 + a * 16 + lq;
#pragma unroll
      for (int kk = 0; kk < 2; ++kk)
        af[a][kk] = *(const bf16x8*)&Al[cur][sidx(row, kk * 64 + lh * 16)];
    }
#pragma unroll
    for (int b = 0; b < NF; ++b) {
      int row = wc * (NF * 16) + b * 16 + lq;
#pragma unroll
      for (int kk = 0; kk < 2; ++kk)
        bfr[b][kk] = *(const bf16x8*)&Bl[cur][sidx(row, kk * 64 + lh * 16)];
    }
#pragma unroll
    for (int kk = 0; kk < 2; ++kk)
#pragma unroll
      for (int a = 0; a < 4; ++a)
#pragma unroll
        for (int b = 0; b < NF; ++b)
          acc[a][b] = __builtin_amdgcn_mfma_f32_16x16x32_bf16(
              af[a][kk], bfr[b][kk], acc[a][b], 0, 0, 0);
    __syncthreads();
    cur ^= 1;
  }

#pragma unroll
  for (int a = 0; a < 4; ++a) {
#pragma unroll
    for (int bb = 0; bb < NF; ++bb) {
      int col = n0 + wc * (NF * 16) + bb * 16 + lq;
      float bv = bias[col];
      int row0 = m0 + wr * 64 + a * 16 + lh * 4;
      if (MODE == 0) {
        unsigned short* O = (unsigned short*)out0;
#pragma unroll
        for (int r = 0; r < 4; ++r)
          O[(long)(row0 + r) * ldo + col] = f2bf(acc[a][bb][r] + bv);
      } else if (MODE == 1) {
        float* O = (float*)out0;
#pragma unroll
        for (int r = 0; r < 4; ++r) {
          float v = acc[a][bb][r] + bv;
          float y = 0.7978845608028654f * (v + 0.044715f * v * v * v);
          O[(long)(row0 + r) * ldo + col] =
              v * __builtin_amdgcn_rcpf(1.f + __expf(-2.f * y));
        }
      } else {
        if (col < H_) {
          unsigned short* O = (unsigned short*)out0;
#pragma unroll
          for (int r = 0; r < 4; ++r)
            O[(long)(row0 + r) * ldo + col] = f2bf(acc[a][bb][r] + bv);
        } else {
          int vcol = col - H_, hh = vcol >> 6, dd = vcol & 63;
          int bi = row0 >> 11, k = row0 & 2047;
          unsigned short t[4];
#pragma unroll
          for (int r = 0; r < 4; ++r) t[r] = f2bf(acc[a][bb][r] + bv);
          *(unsigned long long*)((unsigned short*)out1 +
                                 (((long)(bi * NH_ + hh) * HD_ + dd) << 11) + k) =
              *(unsigned long long*)t;
        }
      }
    }
  }
}

// ---------------- flash attention: 4 waves x 32 q-rows, swizzled LDS --------
// grid (SQ/128, NH, B). KV tiles of 64. K from (B*SK,H); V pre-T (B,NH,HD,SK).
__global__ __launch_bounds__(256) void flash_attn(
    const unsigned short* __restrict__ Qb,
    const unsigned short* __restrict__ Kb,
    const unsigned short* __restrict__ Vtg,
    const int* __restrict__ mask,
    unsigned short* __restrict__ Ob) {
  __shared__ __align__(16) unsigned short Kl[64 * 64];
  __shared__ __align__(16) unsigned short Vt[64 * 64];  // Vt[d][k]
  __shared__ __align__(16) unsigned short Pl[4 * 16 * 64];
  __shared__ float Ml[64];
  const int tid = threadIdx.x;
  const int l = tid & 63, w = tid >> 6;
  const int qb = blockIdx.x, h = blockIdx.y, b = blockIdx.z;
  const int lq = l & 15, lh = l >> 4;

  bf16x8 qf[2][2];
#pragma unroll
  for (int g = 0; g < 2; ++g) {
    long qrow = (long)b * SQ_ + qb * 128 + w * 32 + g * 16 + lq;
    const unsigned short* qp = Qb + qrow * H_ + h * HD_;
    qf[g][0] = *(const bf16x8*)(qp + lh * 8);
    qf[g][1] = *(const bf16x8*)(qp + 32 + lh * 8);
  }

  const int sr = tid >> 2, scs = (tid & 3) * 16;
  const unsigned short* Kg = Kb + ((long)b * SK_ + sr) * H_ + h * HD_ + scs;
  const unsigned short* Vg = Vtg + ((long)(b * NH_ + h) * HD_ + sr) * SK_ + scs;
  const int wi0 = sidx(sr, (tid & 3) * 32);
  const int wi1 = sidx(sr, (tid & 3) * 32 + 16);

  uint4 kr0 = *(const uint4*)Kg, kr1 = *(const uint4*)(Kg + 8);
  uint4 vr0 = *(const uint4*)Vg, vr1 = *(const uint4*)(Vg + 8);
  int mreg = (tid < 64) ? mask[(long)b * SK_ + tid] : 0;
  *(uint4*)&Kl[wi0] = kr0;
  *(uint4*)&Kl[wi1] = kr1;
  *(uint4*)&Vt[wi0] = vr0;
  *(uint4*)&Vt[wi1] = vr1;
  if (tid < 64) Ml[tid] = (float)mreg;

  float m_run[2] = {-INFINITY, -INFINITY}, l_run[2] = {0.f, 0.f};
  f32x4 accO[2][4];
#pragma unroll
  for (int g = 0; g < 2; ++g)
#pragma unroll
    for (int ms = 0; ms < 4; ++ms) accO[g][ms] = (f32x4){0.f, 0.f, 0.f, 0.f};

  const int NT = SK_ / 64;
  for (int kt = 0; kt < NT; ++kt) {
    __syncthreads();  // staged tile visible
    if (kt + 1 < NT) {  // prefetch next tile into regs (overlaps compute)
      const unsigned short* kp = Kg + (long)(kt + 1) * 64 * H_;
      kr0 = *(const uint4*)kp;
      kr1 = *(const uint4*)(kp + 8);
      vr0 = *(const uint4*)(Vg + (kt + 1) * 64);
      vr1 = *(const uint4*)(Vg + (kt + 1) * 64 + 8);
      mreg = (tid < 64) ? mask[(long)b * SK_ + (kt + 1) * 64 + tid] : 0;
    }

    // K and V fragments (read once, reused for both q-groups)
    bf16x8 ka[4][2], va[4][2];
#pragma unroll
    for (int ms = 0; ms < 4; ++ms) {
      int row = ms * 16 + lq;
      ka[ms][0] = *(const bf16x8*)&Kl[sidx(row, lh * 16)];
      ka[ms][1] = *(const bf16x8*)&Kl[sidx(row, 64 + lh * 16)];
      va[ms][0] = *(const bf16x8*)&Vt[sidx(row, lh * 16)];
      va[ms][1] = *(const bf16x8*)&Vt[sidx(row, 64 + lh * 16)];
    }
    f32x4 mv[4];
#pragma unroll
    for (int ms = 0; ms < 4; ++ms) mv[ms] = *(const f32x4*)&Ml[ms * 16 + lh * 4];

#pragma unroll
    for (int g = 0; g < 2; ++g) {
      // S^T(64k x 16q) = K_tile @ Q^T
      f32x4 s[4];
      __builtin_amdgcn_s_setprio(1);
#pragma unroll
      for (int ms = 0; ms < 4; ++ms) {
        f32x4 z = (f32x4){0.f, 0.f, 0.f, 0.f};
        z = __builtin_amdgcn_mfma_f32_16x16x32_bf16(ka[ms][0], qf[g][0], z, 0, 0, 0);
        z = __builtin_amdgcn_mfma_f32_16x16x32_bf16(ka[ms][1], qf[g][1], z, 0, 0, 0);
        s[ms] = z;
      }
      __builtin_amdgcn_s_setprio(0);
      float tmax = -INFINITY;
#pragma unroll
      for (int ms = 0; ms < 4; ++ms)
#pragma unroll
        for (int r = 0; r < 4; ++r) {
          float sv = s[ms][r] * mv[ms][r];
          s[ms][r] = sv;
          tmax = fmaxf(tmax, sv);
        }
      tmax = fmaxf(tmax, __shfl_xor(tmax, 16));
      tmax = fmaxf(tmax, __shfl_xor(tmax, 32));
      float m_new = fmaxf(m_run[g], tmax);
      float sc_ = __expf(m_run[g] - m_new);
      m_run[g] = m_new;
      float lsum = 0.f;
#pragma unroll
      for (int ms = 0; ms < 4; ++ms) {
        unsigned short pu[4];
#pragma unroll
        for (int r = 0; r < 4; ++r) {
          float p = __expf(s[ms][r] - m_new);
          lsum += p;
          pu[r] = f2bf(p);
        }
        *(unsigned long long*)&Pl[w * 1024 +
                                  sidx(lq, ms * 32 + lh * 8)] =
            *(unsigned long long*)pu;
      }
      lsum += __shfl_xor(lsum, 16);
      lsum += __shfl_xor(lsum, 32);
      l_run[g] = l_run[g] * sc_ + lsum;
#pragma unroll
      for (int ms = 0; ms < 4; ++ms)
#pragma unroll
        for (int r = 0; r < 4; ++r) accO[g][ms][r] *= sc_;
      bf16x8 pb0 = *(const bf16x8*)&Pl[w * 1024 + sidx(lq, lh * 16)];
      bf16x8 pb1 = *(const bf16x8*)&Pl[w * 1024 + sidx(lq, 64 + lh * 16)];
      __builtin_amdgcn_s_setprio(1);
#pragma unroll
      for (int ms = 0; ms < 4; ++ms) {
        accO[g][ms] = __builtin_amdgcn_mfma_f32_16x16x32_bf16(va[ms][0], pb0, accO[g][ms], 0, 0, 0);
        accO[g][ms] = __builtin_amdgcn_mfma_f32_16x16x32_bf16(va[ms][1], pb1, accO[g][ms], 0, 0, 0);
      }
      __builtin_amdgcn_s_setprio(0);
    }
    __syncthreads();  // all reads of this tile done
    if (kt + 1 < NT) {
      *(uint4*)&Kl[wi0] = kr0;
      *(uint4*)&Kl[wi1] = kr1;
      *(uint4*)&Vt[wi0] = vr0;
      *(uint4*)&Vt[wi1] = vr1;
      if (tid < 64) Ml[tid] = (float)mreg;
    }
  }

#pragma unroll
  for (int g = 0; g < 2; ++g) {
    float rs = 1.f / l_run[g];
    long orow = (long)b * SQ_ + qb * 128 + w * 32 + g * 16 + lq;
#pragma unroll
    for (int ms = 0; ms < 4; ++ms) {
      unsigned short ou[4];
#pragma unroll
      for (int r = 0; r < 4; ++r) ou[r] = f2bf(accO[g][ms][r] * rs);
      *(unsigned long long*)(Ob + orow * H_ + h * HD_ + ms * 16 + lh * 4) =
          *(unsigned long long*)ou;
    }
  }
}

extern "C" void kernel_launch(void* const* d_in, const int* in_sizes, int n_in,
                              void* d_out, int out_size, void* d_ws, size_t ws_size,
                              hipStream_t stream) {
  (void)in_sizes; (void)n_in; (void)out_size; (void)ws_size;
  const float* attender = (const float*)d_in[0];
  const float* attendee = (const float*)d_in[1];
  const int*   mask     = (const int*)d_in[2];
  const float* c_attn_w = (const float*)d_in[3];
  const float* c_attn_b = (const float*)d_in[4];
  const float* c_proj_w = (const float*)d_in[5];
  const float* c_proj_b = (const float*)d_in[6];
  const float* mlp_w    = (const float*)d_in[7];
  const float* mlp_b    = (const float*)d_in[8];
  float* out = (float*)d_out;

  char* ws = (char*)d_ws;
  size_t off = 0;
  auto alloc = [&](size_t bytes) {
    void* p = ws + off;
    off += (bytes + 255) & ~(size_t)255;
    return p;
  };
  unsigned short* cat   = (unsigned short*)alloc((size_t)4096 * 2048 * 2); // [attender_bf | proj_bf]
  unsigned short* aet   = (unsigned short*)alloc((size_t)4096 * 1024 * 2);
  unsigned short* w_atT = (unsigned short*)alloc((size_t)3072 * 1024 * 2); // (3H, H)
  unsigned short* w_prT = (unsigned short*)alloc((size_t)1024 * 1024 * 2);
  unsigned short* w_mlT = (unsigned short*)alloc((size_t)1024 * 2048 * 2); // (H, 2H)
  unsigned short* Qb    = (unsigned short*)alloc((size_t)4096 * 1024 * 2);
  unsigned short* Kbuf  = (unsigned short*)alloc((size_t)4096 * 1024 * 2);
  unsigned short* Vtg   = (unsigned short*)alloc((size_t)B_ * NH_ * HD_ * SK_ * 2);
  unsigned short* attnb = (unsigned short*)alloc((size_t)4096 * 1024 * 2);

  conv_bf16<<<2048, 256, 0, stream>>>(attender, cat, 4096, 1024, 1024, 2048);
  conv_bf16<<<2048, 256, 0, stream>>>(attendee, aet, 4096, 1024, 1024, 1024);
  convT<<<768, 256, 0, stream>>>(c_attn_w, w_atT, 1024, 3072);
  convT<<<256, 256, 0, stream>>>(c_proj_w, w_prT, 1024, 1024);
  convT<<<512, 256, 0, stream>>>(mlp_w, w_mlT, 2048, 1024);

  // Q = attender @ W[:, :H] + b[:H]
  gemm_bt<2, 0><<<dim3(16, 32), 256, 0, stream>>>(
      cat, 2048, w_atT, 1024, c_attn_b, Qb, nullptr, 1024, 4096, 1024, 1024);
  // K,V = attendee @ W[:, H:3H] + b[H:3H]; K normal, V transposed
  gemm_bt<4, 2><<<dim3(16, 32), 256, 0, stream>>>(
      aet, 1024, w_atT + (size_t)1024 * 1024, 1024, c_attn_b + 1024,
      Kbuf, Vtg, 1024, 4096, 2048, 1024);
  // attention
  flash_attn<<<dim3(16, 16, 2), 256, 0, stream>>>(Qb, Kbuf, Vtg, mask, attnb);
  // proj -> cat[:, H:2H]
  gemm_bt<2, 0><<<dim3(16, 32), 256, 0, stream>>>(
      attnb, 1024, w_prT, 1024, c_proj_b, cat + 1024, nullptr, 2048, 4096, 1024, 1024);
  // out = gelu(cat @ mlp_w + mlp_b), f32
  gemm_bt<2, 1><<<dim3(16, 32), 256, 0, stream>>>(
      cat, 2048, w_mlT, 2048, mlp_b, out, nullptr, 1024, 4096, 1024, 2048);
}